// Round 1
// 201.974 us; speedup vs baseline: 1.0159x; 1.0159x over previous
//
#include <hip/hip_runtime.h>

// Problem constants: B=16384, D_in=512, H=512
#define M_ROWS 16384
#define N_COLS 1536   // 3*H
#define K_DIM  512
#define H_DIM  512
#define NT     8      // K_DIM / 64 K-tiles

typedef __attribute__((ext_vector_type(8))) short short8;   // 8 bf16 = 4 VGPRs
typedef __attribute__((ext_vector_type(16))) float f32x16;  // 32x32 MFMA acc

__device__ __forceinline__ unsigned short f2bf(float f) {
  unsigned u = __float_as_uint(f);
  u += 0x7fffu + ((u >> 16) & 1u);   // RNE
  return (unsigned short)(u >> 16);
}
__device__ __forceinline__ float bf2f(unsigned short h) {
  return __uint_as_float(((unsigned)h) << 16);
}

__device__ __forceinline__ void gload_lds16(const void* g, void* l) {
  __builtin_amdgcn_global_load_lds((const __attribute__((address_space(1))) void*)g,
                                   (__attribute__((address_space(3))) void*)l,
                                   16, 0, 0);
}

// ---------------- fp32 -> bf16 convert, all 4 buffers in one launch ----------
__global__ __launch_bounds__(256) void cvt_all(
    const float* __restrict__ x, const float* __restrict__ hx,
    const float* __restrict__ Wi, const float* __restrict__ Wh,
    unsigned short* __restrict__ xb, unsigned short* __restrict__ hxb,
    unsigned short* __restrict__ Wib, unsigned short* __restrict__ Whb) {
  int i = blockIdx.x * blockDim.x + threadIdx.x;   // grid exactly 4587520 threads
  const float* s; unsigned short* d; int off;
  if (i < 2097152)      { s = x;  d = xb;  off = i; }
  else if (i < 4194304) { s = hx; d = hxb; off = i - 2097152; }
  else if (i < 4390912) { s = Wi; d = Wib; off = i - 4194304; }
  else                  { s = Wh; d = Whb; off = i - 4390912; }
  float4 f = ((const float4*)s)[off];
  ushort4 u;
  u.x = f2bf(f.x); u.y = f2bf(f.y); u.z = f2bf(f.z); u.w = f2bf(f.w);
  ((ushort4*)d)[off] = u;
}

// ---------------- GEMM (bf16 MFMA 32x32x16) + bias, permuted store ----------
// C[m][n] = sum_k A[m][k]*W[n][k] + bias[n].  blockIdx.z: 0=(x,Wi,bi,xt) 1=(hx,Wh,bh,ht)
// v2: 256x256 tile, BK=64, 8 waves (2M x 4N), wave tile 128x64 (4x2 of 32x32x16).
// Deep pipeline: 2 LDS buffers, prefetch distance 2 K-tiles, counted vmcnt(8)
// (never drains to 0 in-loop), raw s_barrier + fences, setprio around MFMA.
// LDS XOR swizzle: 16B chunk c of row r stored at physical chunk c^(r&7)
// (applied by pre-swizzling the per-lane GLOBAL source address; LDS dest linear).
// Store permutation within each aligned 64-col group: value for true col
// 32*j + c (c=lane&31, j=0..1) stored at slot 2c+j  -> finalize decode unchanged.
__global__ __launch_bounds__(512, 2) void gemm_bf16(
    const unsigned short* __restrict__ xb, const unsigned short* __restrict__ hxb,
    const unsigned short* __restrict__ Wib, const unsigned short* __restrict__ Whb,
    const float* __restrict__ b_i2h, const float* __restrict__ b_h2h,
    unsigned short* __restrict__ xt, unsigned short* __restrict__ ht) {
  const int mat = blockIdx.z;
  const unsigned short* A  = mat ? hxb : xb;
  const unsigned short* Bw = mat ? Whb : Wib;
  const float* bias        = mat ? b_h2h : b_i2h;
  unsigned short* outp     = mat ? ht : xt;

  // XCD-aware bijective swizzle over the 64x6 tile grid (384 wgs = 8 XCDs * 48):
  // XCD c gets 8 consecutive m-panels x all 6 n-panels -> A reuse is L2-local.
  const int l  = blockIdx.x + 64 * blockIdx.y;
  const int wg = (l & 7) * 48 + (l >> 3);
  const int mb = (wg / 6) * 256;
  const int nb = (wg % 6) * 256;

  // A: [2 buf][256][64] at 0,  B: [2 buf][256][64] at 32768  (128 KiB total)
  __shared__ short lds[65536];

  const int t = threadIdx.x;
  const int w = t >> 6, lane = t & 63;
  const int wr = w >> 2, wc = w & 3;            // wave tile (wr*128, wc*64)
  const int l31 = lane & 31, h = lane >> 5;
  const int srow = lane >> 3;                   // 0..7 row within 8-row seg
  const int scol = ((lane & 7) ^ srow) * 8;     // XOR-swizzled source chunk

  // Stage K-tile kt into buffer kt&1.  8 gload_lds16 per wave (A0B0..A3B3).
  auto stage = [&](int kt) {
    short* sA = lds + (kt & 1) * 16384;
    short* sB = lds + 32768 + (kt & 1) * 16384;
    const int k0 = kt * 64;
#pragma unroll
    for (int q = 0; q < 4; ++q) {
      const int br = q * 64 + w * 8;            // wave-uniform row base
      gload_lds16(A  + (size_t)(mb + br + srow) * K_DIM + k0 + scol, &sA[br * 64]);
      gload_lds16(Bw + (size_t)(nb + br + srow) * K_DIM + k0 + scol, &sB[br * 64]);
    }
  };

  stage(0);
  stage(1);

  f32x16 acc[4][2];
#pragma unroll
  for (int i = 0; i < 4; ++i)
#pragma unroll
    for (int j = 0; j < 2; ++j)
#pragma unroll
      for (int r = 0; r < 16; ++r) acc[i][j][r] = 0.f;

  asm volatile("s_waitcnt vmcnt(8)" ::: "memory");   // tile0 landed (tile1 in flight)
  __builtin_amdgcn_s_barrier();
  asm volatile("" ::: "memory");

  for (int kt = 0; kt < NT; ++kt) {
    const short* lA = lds + (kt & 1) * 16384;
    const short* lB = lds + 32768 + (kt & 1) * 16384;
    // 4 barrier-free phases; compiler inserts fine-grained lgkmcnt for ds->MFMA.
#pragma unroll
    for (int kk = 0; kk < 4; ++kk) {
      // lane needs k = kk*16 + h*8 + j -> logical chunk kk*2+h,
      // physical chunk (kk*2+h) ^ (row&7), row&7 == l31&7 here.
      const int chunk = ((kk * 2 + h) ^ (l31 & 7)) * 8;
      short8 af[4], bfr[2];
#pragma unroll
      for (int i = 0; i < 4; ++i)
        af[i] = *(const short8*)&lA[(wr * 128 + i * 32 + l31) * 64 + chunk];
#pragma unroll
      for (int j = 0; j < 2; ++j)
        bfr[j] = *(const short8*)&lB[(wc * 64 + j * 32 + l31) * 64 + chunk];
      __builtin_amdgcn_s_setprio(1);
#pragma unroll
      for (int i = 0; i < 4; ++i)
#pragma unroll
        for (int j = 0; j < 2; ++j)
          acc[i][j] = __builtin_amdgcn_mfma_f32_32x32x16_bf16(af[i], bfr[j], acc[i][j], 0, 0, 0);
      __builtin_amdgcn_s_setprio(0);
    }
    if (kt < NT - 1) {
      asm volatile("" ::: "memory");
      __builtin_amdgcn_s_barrier();          // WAR: all waves done reading buf kt&1
      asm volatile("" ::: "memory");
      if (kt < NT - 2) {
        stage(kt + 2);                       // refill just-freed buffer (same parity)
        // wait for tile kt+1 (issued one full tile ago); kt+2's 8 stay in flight
        asm volatile("s_waitcnt vmcnt(8)" ::: "memory");
      } else {
        asm volatile("s_waitcnt vmcnt(0)" ::: "memory");   // last tile: drain
      }
      __builtin_amdgcn_s_barrier();          // RAW: tile kt+1 visible to all waves
      asm volatile("" ::: "memory");
    }
  }

  // Epilogue: bias + packed permuted ushort2 store.
  // C/D: col=l31, row=(reg&3)+8*(reg>>2)+4*h  (identical to v1, finalize unchanged)
  const float biasj0 = bias[nb + wc * 64 + l31];
  const float biasj1 = bias[nb + wc * 64 + 32 + l31];
#pragma unroll
  for (int i = 0; i < 4; ++i) {
#pragma unroll
    for (int g = 0; g < 4; ++g) {
#pragma unroll
      for (int d = 0; d < 4; ++d) {
        const int reg = g * 4 + d;
        const int row = d + 8 * g + 4 * h;
        ushort2 pk;
        pk.x = f2bf(acc[i][0][reg] + biasj0);
        pk.y = f2bf(acc[i][1][reg] + biasj1);
        *(ushort2*)(outp + (size_t)(mb + wr * 128 + i * 32 + row) * N_COLS +
                    nb + wc * 64 + 2 * l31) = pk;
      }
    }
  }
}

// ---------------- finalize: wave-per-row, b128 loads, float4 hx/out ---------
// Permuted slot s (within aligned 64-group) holds true col 32*(s&1)+(s>>1).
__global__ __launch_bounds__(256) void finalize_kernel(
    const unsigned short* __restrict__ xt, const unsigned short* __restrict__ ht,
    const unsigned short* __restrict__ hxb, float* __restrict__ out) {
  const int w = threadIdx.x >> 6, lane = threadIdx.x & 63;
  const int b = blockIdx.x * 4 + w;            // one row per wave
  const size_t rb = (size_t)b * N_COLS;

  short8 sxr = *(const short8*)&xt[rb + 8 * lane];
  short8 sxz = *(const short8*)&xt[rb + 512 + 8 * lane];
  short8 sxn = *(const short8*)&xt[rb + 1024 + 8 * lane];
  short8 shr = *(const short8*)&ht[rb + 8 * lane];
  short8 shz = *(const short8*)&ht[rb + 512 + 8 * lane];
  short8 shn = *(const short8*)&ht[rb + 1024 + 8 * lane];

  float vxr[8], vxz[8], vxn[8], vhr[8], vhz[8], vhn[8];
#pragma unroll
  for (int k = 0; k < 8; ++k) {
    vxr[k] = bf2f((unsigned short)sxr[k]);
    vxz[k] = bf2f((unsigned short)sxz[k]);
    vxn[k] = bf2f((unsigned short)sxn[k]);
    vhr[k] = bf2f((unsigned short)shr[k]);
    vhz[k] = bf2f((unsigned short)shz[k]);
    vhn[k] = bf2f((unsigned short)shn[k]);
  }

  float pr[8] = {0.f, 0.f, 0.f, 0.f, 0.f, 0.f, 0.f, 0.f};
#pragma unroll
  for (int k = 0; k < 8; ++k) {
    pr[0] += vxr[k] + vxz[k];
    pr[1] += vxr[k] * vxr[k] + vxz[k] * vxz[k];
    pr[2] += vxn[k];
    pr[3] += vxn[k] * vxn[k];
    pr[4] += vhr[k] + vhz[k];
    pr[5] += vhr[k] * vhr[k] + vhz[k] * vhz[k];
    pr[6] += vhn[k];
    pr[7] += vhn[k] * vhn[k];
  }
#pragma unroll
  for (int msk = 1; msk < 64; msk <<= 1)
#pragma unroll
    for (int k = 0; k < 8; ++k) pr[k] += __shfl_xor(pr[k], msk);

  const float inv2H = 1.f / 1024.f, invH = 1.f / 512.f;
  const float mx0 = pr[0] * inv2H;
  const float ix0 = rsqrtf(pr[1] * inv2H - mx0 * mx0 + 1e-5f);
  const float mx1 = pr[2] * invH;
  const float ix1 = rsqrtf(pr[3] * invH - mx1 * mx1 + 1e-5f);
  const float mh0 = pr[4] * inv2H;
  const float ih0 = rsqrtf(pr[5] * inv2H - mh0 * mh0 + 1e-5f);
  const float mh1 = pr[6] * invH;
  const float ih1 = rsqrtf(pr[7] * invH - mh1 * mh1 + 1e-5f);

  auto calc = [&](float xrv, float xzv, float xnv, float hrv, float hzv,
                  float hnv, float hxs) -> float {
    float ar = (xrv - mx0) * ix0 + (hrv - mh0) * ih0;
    float az = (xzv - mx0) * ix0 + (hzv - mh0) * ih0;
    float r = 1.f / (1.f + __expf(-ar));
    float z = 1.f / (1.f + __expf(-az));
    float arg = (xnv - mx1) * ix1 + r * ((hnv - mh1) * ih1);
    float e2 = __expf(2.f * arg);
    float nn = (e2 - 1.f) / (e2 + 1.f);
    return z * hxs + (1.f - z) * nn;
  };

  const int base4 = 64 * (lane >> 3) + 4 * (lane & 7);
  const unsigned short* hxrow = hxb + (size_t)b * H_DIM;
  float* orow = out + (size_t)b * H_DIM;

  ushort4 hx0u = *(const ushort4*)&hxrow[base4];
  ushort4 hx1u = *(const ushort4*)&hxrow[base4 + 32];
  float hx0[4] = {bf2f(hx0u.x), bf2f(hx0u.y), bf2f(hx0u.z), bf2f(hx0u.w)};
  float hx1[4] = {bf2f(hx1u.x), bf2f(hx1u.y), bf2f(hx1u.z), bf2f(hx1u.w)};

  float4 r0, r1;
  float* r0p = (float*)&r0;
  float* r1p = (float*)&r1;
#pragma unroll
  for (int k = 0; k < 4; ++k) {
    r0p[k] = calc(vxr[2 * k], vxz[2 * k], vxn[2 * k],
                  vhr[2 * k], vhz[2 * k], vhn[2 * k], hx0[k]);
    r1p[k] = calc(vxr[2 * k + 1], vxz[2 * k + 1], vxn[2 * k + 1],
                  vhr[2 * k + 1], vhz[2 * k + 1], vhn[2 * k + 1], hx1[k]);
  }
  *(float4*)&orow[base4] = r0;
  *(float4*)&orow[base4 + 32] = r1;
}

// ---------------- launch ----------------
// Workspace layout (bytes):            offset        size
//   xb  (bf16 x,  16384x512)               0      16777216
//   hxb (bf16 hx, 16384x512)        16777216      16777216
//   Wib (bf16,  1536x512)           33554432       1572864
//   Whb (bf16,  1536x512)           35127296       1572864
//   xt  (bf16, 16384x1536, permuted) 36700160     50331648
//   ht  (bf16, 16384x1536, permuted) 87031808     50331648
extern "C" void kernel_launch(void* const* d_in, const int* in_sizes, int n_in,
                              void* d_out, int out_size, void* d_ws, size_t ws_size,
                              hipStream_t stream) {
  const float* x  = (const float*)d_in[0];
  const float* hx = (const float*)d_in[1];
  const float* Wi = (const float*)d_in[2];
  const float* bi = (const float*)d_in[3];
  const float* Wh = (const float*)d_in[4];
  const float* bh = (const float*)d_in[5];
  float* out = (float*)d_out;

  char* ws = (char*)d_ws;
  unsigned short* xb  = (unsigned short*)(ws);
  unsigned short* hxb = (unsigned short*)(ws + 16777216);
  unsigned short* Wib = (unsigned short*)(ws + 33554432);
  unsigned short* Whb = (unsigned short*)(ws + 35127296);
  unsigned short* xt  = (unsigned short*)(ws + 36700160);
  unsigned short* ht  = (unsigned short*)(ws + 87031808);

  cvt_all<<<17920, 256, 0, stream>>>(x, hx, Wi, Wh, xb, hxb, Wib, Whb);

  gemm_bf16<<<dim3(64, 6, 2), 512, 0, stream>>>(
      xb, hxb, Wib, Whb, bi, bh, xt, ht);

  finalize_kernel<<<M_ROWS / 4, 256, 0, stream>>>(xt, ht, hxb, out);
}